// Round 6
// baseline (271.451 us; speedup 1.0000x reference)
//
#include <hip/hip_runtime.h>
#include <hip/hip_bf16.h>

// Problem constants
// B=64, N=256, IN=512, OUT=512, K_SLOTS=8, DK=64
// inputs: node_feats (64*256*512 f32), adj (64*8*256*256 f32), weight (512*512 f32), bias (512 f32)
// out: (64*256*512) f32
//
// Round-6 design. Evidence so far:
//  - harness fills (~158us) are inside dur_us; controllable kernel budget
//    is ~100us now vs ~40us HBM floor.
//  - register-direct fragment gathers are poison (rounds 1-4).
//  - round-5 (both operands through LDS) is LDS-pipe-bound: 1.25 LDS
//    b128 reads/MFMA + heavy ds_write traffic.
// Fix: B operands (W, h) are OURS to lay out -> store them pre-packed in
// MFMA fragment order, so B-frags are single coalesced 16B/lane GLOBAL loads
// (L1/L2-hot, identical across waves). Only the streamed A operands (X, adj)
// stage through LDS. Wave tile 32 rows x 64 cols -> 0.25 LDS reads/MFMA.
//   Wfrag[ks][kb(16)][dt(4)][dloc(16)][kk(32)]  (bf16, 512 KB)
//   hFrag[b][ks][mt(8)][dt(4)][dloc(16)][mm(32)] (bf16, 16.8 MB)

typedef __attribute__((ext_vector_type(8))) short short8;   // 8 bf16 (4 VGPRs)
typedef __attribute__((ext_vector_type(4))) float floatx4;  // MFMA C/D frag

__device__ __forceinline__ unsigned short f2bf(float f) {
    union { float f; unsigned u; } v; v.f = f;
    unsigned r = v.u + 0x7FFFu + ((v.u >> 16) & 1u);  // RNE
    return (unsigned short)(r >> 16);
}

// packed f32x2 -> bf16x2 (RNE); compiles to v_cvt_pk_bf16_f32 on gfx950
__device__ __forceinline__ unsigned pk2bf(float a, float b) {
    union { __hip_bfloat162 h; unsigned u; } cv;
    cv.h = __float22bfloat162_rn(make_float2(a, b));
    return cv.u;
}

// ---------------------------------------------------------------------------
// wfrag_kernel: W (512x512 [k][o] f32) -> Wfrag bf16, fragment order:
//   Wfrag[(ks*16+kb)*2048 + (dt*16+dloc)*32 + kk] = W[kb*32+kk][ks*64+dt*16+dloc]
// 128 blocks = (ks, kb); per block a 32k x 64o tile through LDS transpose.
// ---------------------------------------------------------------------------
__global__ __launch_bounds__(256) void wfrag_kernel(const float* __restrict__ W,
                                                    unsigned short* __restrict__ Wf) {
    __shared__ unsigned short t[32 * 66];   // [krow][ocol], pad 66 (bank-clean)
    const int blk = blockIdx.x;             // = ks*16 + kb
    const int k0 = (blk & 15) * 32;
    const int o0 = (blk >> 4) * 64;
    const int tid = threadIdx.x;
#pragma unroll
    for (int j = 0; j < 8; ++j) {
        int idx = tid + j * 256;            // 0..2047
        int oc = idx & 63, kr = idx >> 6;
        t[kr * 66 + oc] = f2bf(W[(size_t)(k0 + kr) * 512 + o0 + oc]);
    }
    __syncthreads();
#pragma unroll
    for (int j = 0; j < 8; ++j) {
        int idx = tid + j * 256;
        int kk = idx & 31, dr = idx >> 5;   // dr = dt*16+dloc
        Wf[(size_t)blk * 2048 + dr * 32 + kk] = t[kk * 66 + dr];
    }
}

// ---------------------------------------------------------------------------
// lin_kernel: h = relu(X@Wslice + bias), written straight into hFrag order.
// 1024 blocks = (b, ks, mh); 256 thr = 4 waves; block tile 128 m x 64 d over
// k=512 (16 steps of 32).  LDS: X-tile [128][40] bf16 dbuf = 20 KB.
// Per step per wave: 2 LDS b128 A-frag reads + 4 global 16B B-frag loads
// (Wfrag slice, L1/L2-hot, identical across waves) + 8 MFMA.
// Single-register-set T14 staging: WRITE(buf^1, r); LOAD(r, s+2); COMP(buf).
// ---------------------------------------------------------------------------
__global__ __launch_bounds__(256, 5) void lin_kernel(
    const float* __restrict__ X, const unsigned short* __restrict__ Wf,
    const float* __restrict__ bias, unsigned short* __restrict__ hF) {
    __shared__ unsigned short xt[2][128 * 40];

    const int W_ = (blockIdx.x & 7) * 128 + (blockIdx.x >> 3);  // XCD chunk
    const int mh = W_ & 1;
    const int ks = (W_ >> 1) & 7;
    const int b  = W_ >> 4;

    const int tid = threadIdx.x;
    const int lane = tid & 63, w = tid >> 6;     // wave 0..3
    const int lrow = lane & 15, quad = lane >> 4;

    // staging: thread = 64 B (16 f32) of one m-row; wave covers 32 rows coalesced
    const float* xsrc = X + (size_t)b * 131072
                          + (size_t)(mh * 128 + (tid >> 1)) * 512 + (tid & 1) * 16;
    const int xw = (tid >> 1) * 40 + (tid & 1) * 16;

    // B-frag base: + kb*2048 + dt*512 (elements)
    const unsigned short* wfp = Wf + (size_t)ks * 32768 + lrow * 32 + quad * 8;

    float bv[4];
#pragma unroll
    for (int dt = 0; dt < 4; ++dt) bv[dt] = bias[ks * 64 + dt * 16 + lrow];

    floatx4 acc[2][4];
    const floatx4 fzero = {0.f, 0.f, 0.f, 0.f};
#pragma unroll
    for (int g = 0; g < 2; ++g)
#pragma unroll
        for (int j = 0; j < 4; ++j) acc[g][j] = fzero;

    float4 r[4];
#define LLOAD(kb) do {                                                  \
        r[0] = *(const float4*)(xsrc + (kb) * 32);                      \
        r[1] = *(const float4*)(xsrc + (kb) * 32 + 4);                  \
        r[2] = *(const float4*)(xsrc + (kb) * 32 + 8);                  \
        r[3] = *(const float4*)(xsrc + (kb) * 32 + 12);                 \
    } while (0)
#define LWRITE(buf) do {                                                \
        union { short8 s; unsigned u[4]; } t0_, t1_;                    \
        t0_.u[0] = pk2bf(r[0].x, r[0].y); t0_.u[1] = pk2bf(r[0].z, r[0].w); \
        t0_.u[2] = pk2bf(r[1].x, r[1].y); t0_.u[3] = pk2bf(r[1].z, r[1].w); \
        t1_.u[0] = pk2bf(r[2].x, r[2].y); t1_.u[1] = pk2bf(r[2].z, r[2].w); \
        t1_.u[2] = pk2bf(r[3].x, r[3].y); t1_.u[3] = pk2bf(r[3].z, r[3].w); \
        *(short8*)(xt[buf] + xw) = t0_.s;                               \
        *(short8*)(xt[buf] + xw + 8) = t1_.s;                           \
    } while (0)

    LLOAD(0);
    LWRITE(0);
    LLOAD(1);
    __syncthreads();

#pragma unroll
    for (int kb = 0; kb < 16; ++kb) {
        const int buf = kb & 1;
        if (kb < 15) {
            LWRITE(buf ^ 1);
            if (kb < 14) LLOAD(kb + 2);      // in flight over compute+barrier
        }
        short8 a0 = *(const short8*)(xt[buf] + (w * 32 + lrow) * 40 + quad * 8);
        short8 a1 = *(const short8*)(xt[buf] + (w * 32 + 16 + lrow) * 40 + quad * 8);
#pragma unroll
        for (int dt = 0; dt < 4; ++dt) {
            short8 wfr = *(const short8*)(wfp + kb * 2048 + dt * 512);
            acc[0][dt] = __builtin_amdgcn_mfma_f32_16x16x32_bf16(a0, wfr, acc[0][dt], 0, 0, 0);
            acc[1][dt] = __builtin_amdgcn_mfma_f32_16x16x32_bf16(a1, wfr, acc[1][dt], 0, 0, 0);
        }
        if (kb < 15) __syncthreads();
    }
#undef LLOAD
#undef LWRITE

    // epilogue -> hFrag: C row (quad*4+reg) = m, col (lane&15) = d.
    // mt = mh*4 + w (g*16+quad*4+reg < 32); 4 consecutive m -> one 8-B store.
    unsigned short* hs = hF + (size_t)(b * 8 + ks) * 16384 + (size_t)(mh * 4 + w) * 2048;
#pragma unroll
    for (int g = 0; g < 2; ++g) {
#pragma unroll
        for (int dt = 0; dt < 4; ++dt) {
            floatx4 c = acc[g][dt];
            uint2 pv;
            pv.x = pk2bf(fmaxf(c.x + bv[dt], 0.f), fmaxf(c.y + bv[dt], 0.f));
            pv.y = pk2bf(fmaxf(c.z + bv[dt], 0.f), fmaxf(c.w + bv[dt], 0.f));
            *(uint2*)(hs + dt * 512 + lrow * 32 + g * 16 + quad * 4) = pv;
        }
    }
}

// ---------------------------------------------------------------------------
// agg_kernel: out = adj @ h.  1024 blocks = (b, ks, nt); 256 thr = 4 waves;
// block tile 128 n x 64 d over m=256 (8 steps of 32).
// LDS: adj-tile [128][40] bf16 dbuf = 20 KB.  adj staged coalesced (each
// 128-B line fetched exactly once); B-frags are 16B/lane global loads from
// hFrag (32 KB slice, L1/L2-hot, identical across the 4 waves).
// ---------------------------------------------------------------------------
__global__ __launch_bounds__(256, 5) void agg_kernel(
    const unsigned short* __restrict__ hF, const float* __restrict__ adj,
    float* __restrict__ out) {
    __shared__ unsigned short at[2][128 * 40];

    const int W_ = (blockIdx.x & 7) * 128 + (blockIdx.x >> 3);  // XCD chunk
    const int nt = W_ & 1;
    const int ks = (W_ >> 1) & 7;
    const int b  = W_ >> 4;

    const int tid = threadIdx.x;
    const int lane = tid & 63, w = tid >> 6;     // wave 0..3
    const int lrow = lane & 15, quad = lane >> 4;

    const float* asrc = adj + (size_t)(b * 8 + ks) * 65536
                            + (size_t)(nt * 128 + (tid >> 1)) * 256 + (tid & 1) * 16;
    const int aw = (tid >> 1) * 40 + (tid & 1) * 16;

    // B-frag base: + mt*2048 + dt*512 (elements)
    const unsigned short* hfp = hF + (size_t)(b * 8 + ks) * 16384 + lrow * 32 + quad * 8;

    floatx4 acc[2][4];
    const floatx4 fzero = {0.f, 0.f, 0.f, 0.f};
#pragma unroll
    for (int g = 0; g < 2; ++g)
#pragma unroll
        for (int j = 0; j < 4; ++j) acc[g][j] = fzero;

    float4 r[4];
#define ALOAD(mt) do {                                                  \
        r[0] = *(const float4*)(asrc + (mt) * 32);                      \
        r[1] = *(const float4*)(asrc + (mt) * 32 + 4);                  \
        r[2] = *(const float4*)(asrc + (mt) * 32 + 8);                  \
        r[3] = *(const float4*)(asrc + (mt) * 32 + 12);                 \
    } while (0)
#define AWRITE(buf) do {                                                \
        union { short8 s; unsigned u[4]; } t0_, t1_;                    \
        t0_.u[0] = pk2bf(r[0].x, r[0].y); t0_.u[1] = pk2bf(r[0].z, r[0].w); \
        t0_.u[2] = pk2bf(r[1].x, r[1].y); t0_.u[3] = pk2bf(r[1].z, r[1].w); \
        t1_.u[0] = pk2bf(r[2].x, r[2].y); t1_.u[1] = pk2bf(r[2].z, r[2].w); \
        t1_.u[2] = pk2bf(r[3].x, r[3].y); t1_.u[3] = pk2bf(r[3].z, r[3].w); \
        *(short8*)(at[buf] + aw) = t0_.s;                               \
        *(short8*)(at[buf] + aw + 8) = t1_.s;                           \
    } while (0)

    ALOAD(0);
    AWRITE(0);
    ALOAD(1);
    __syncthreads();

#pragma unroll
    for (int mt = 0; mt < 8; ++mt) {
        const int buf = mt & 1;
        if (mt < 7) {
            AWRITE(buf ^ 1);
            if (mt < 6) ALOAD(mt + 2);
        }
        short8 a0 = *(const short8*)(at[buf] + (w * 32 + lrow) * 40 + quad * 8);
        short8 a1 = *(const short8*)(at[buf] + (w * 32 + 16 + lrow) * 40 + quad * 8);
#pragma unroll
        for (int dt = 0; dt < 4; ++dt) {
            short8 hfr = *(const short8*)(hfp + mt * 2048 + dt * 512);
            acc[0][dt] = __builtin_amdgcn_mfma_f32_16x16x32_bf16(a0, hfr, acc[0][dt], 0, 0, 0);
            acc[1][dt] = __builtin_amdgcn_mfma_f32_16x16x32_bf16(a1, hfr, acc[1][dt], 0, 0, 0);
        }
        if (mt < 7) __syncthreads();
    }
#undef ALOAD
#undef AWRITE

    // epilogue: C row (quad*4+reg) = n, col (lane&15) = d
#pragma unroll
    for (int g = 0; g < 2; ++g) {
        const int n0 = nt * 128 + w * 32 + g * 16 + quad * 4;
        float* dst = out + ((size_t)b * 256 + n0) * 512 + ks * 64 + lrow;
#pragma unroll
        for (int dt = 0; dt < 4; ++dt) {
            float* p = dst + dt * 16;
            p[0 * 512] = acc[g][dt].x;
            p[1 * 512] = acc[g][dt].y;
            p[2 * 512] = acc[g][dt].z;
            p[3 * 512] = acc[g][dt].w;
        }
    }
}

// ---------------------------------------------------------------------------
extern "C" void kernel_launch(void* const* d_in, const int* in_sizes, int n_in,
                              void* d_out, int out_size, void* d_ws, size_t ws_size,
                              hipStream_t stream) {
    const float* X    = (const float*)d_in[0];  // node_feats
    const float* adj  = (const float*)d_in[1];  // adj
    const float* W    = (const float*)d_in[2];  // weight
    const float* bias = (const float*)d_in[3];  // bias
    float* out = (float*)d_out;

    // workspace: Wfrag bf16 (512 KB) then hFrag bf16 (16.8 MB)
    unsigned short* Wf = (unsigned short*)d_ws;
    unsigned short* hF = Wf + 512 * 512;

    wfrag_kernel<<<128, 256, 0, stream>>>(W, Wf);
    lin_kernel<<<1024, 256, 0, stream>>>(X, Wf, bias, hF);
    agg_kernel<<<1024, 256, 0, stream>>>(hF, adj, out);
}

// Round 7
// 262.782 us; speedup vs baseline: 1.0330x; 1.0330x over previous
//
#include <hip/hip_runtime.h>
#include <hip/hip_bf16.h>

// Problem constants
// B=64, N=256, IN=512, OUT=512, K_SLOTS=8, DK=64
// inputs: node_feats (64*256*512 f32), adj (64*8*256*256 f32), weight (512*512 f32), bias (512 f32)
// out: (64*256*512) f32
//
// Round-7 design. Root cause of rounds 2-6 (~2.5x above HBM floor):
// hipcc drains vmcnt(0) before every __syncthreads() [m97 asm evidence],
// killing every cross-barrier global prefetch. Every step paid full load
// latency serially. Fix: raw s_barrier + lgkmcnt(0) only (no vmcnt drain),
// so A-tile loads (2 steps ahead) and B-frag loads (1 step ahead) stay in
// flight across barriers. Single-buffer LDS, write-bar-read-bar discipline.
//   Wfrag[ks][kb(16)][dt(4)][dloc(16)][kk(32)]  (bf16, 512 KB)
//   hFrag[b][ks][mt(8)][dt(4)][dloc(16)][mm(32)] (bf16, 16.8 MB)

typedef __attribute__((ext_vector_type(8))) short short8;   // 8 bf16 (4 VGPRs)
typedef __attribute__((ext_vector_type(4))) float floatx4;  // MFMA C/D frag

__device__ __forceinline__ unsigned short f2bf(float f) {
    union { float f; unsigned u; } v; v.f = f;
    unsigned r = v.u + 0x7FFFu + ((v.u >> 16) & 1u);  // RNE
    return (unsigned short)(r >> 16);
}

// packed f32x2 -> bf16x2 (RNE); compiles to v_cvt_pk_bf16_f32 on gfx950
__device__ __forceinline__ unsigned pk2bf(float a, float b) {
    union { __hip_bfloat162 h; unsigned u; } cv;
    cv.h = __float22bfloat162_rn(make_float2(a, b));
    return cv.u;
}

// Raw workgroup barrier WITHOUT the vmcnt(0) drain __syncthreads carries.
// lgkmcnt(0): my ds_writes/ds_reads retired; global loads stay in flight.
__device__ __forceinline__ void lds_barrier() {
    __builtin_amdgcn_sched_barrier(0);
    asm volatile("s_waitcnt lgkmcnt(0)" ::: "memory");
    __builtin_amdgcn_s_barrier();
    __builtin_amdgcn_sched_barrier(0);
}

// ---------------------------------------------------------------------------
// wfrag_kernel: W (512x512 [k][o] f32) -> Wfrag bf16, fragment order:
//   Wfrag[(ks*16+kb)*2048 + (dt*16+dloc)*32 + kk] = W[kb*32+kk][ks*64+dt*16+dloc]
// ---------------------------------------------------------------------------
__global__ __launch_bounds__(256) void wfrag_kernel(const float* __restrict__ W,
                                                    unsigned short* __restrict__ Wf) {
    __shared__ unsigned short t[32 * 66];
    const int blk = blockIdx.x;             // = ks*16 + kb
    const int k0 = (blk & 15) * 32;
    const int o0 = (blk >> 4) * 64;
    const int tid = threadIdx.x;
#pragma unroll
    for (int j = 0; j < 8; ++j) {
        int idx = tid + j * 256;            // 0..2047
        int oc = idx & 63, kr = idx >> 6;
        t[kr * 66 + oc] = f2bf(W[(size_t)(k0 + kr) * 512 + o0 + oc]);
    }
    __syncthreads();
#pragma unroll
    for (int j = 0; j < 8; ++j) {
        int idx = tid + j * 256;
        int kk = idx & 31, dr = idx >> 5;   // dr = dt*16+dloc
        Wf[(size_t)blk * 2048 + dr * 32 + kk] = t[kk * 66 + dr];
    }
}

// ---------------------------------------------------------------------------
// lin_kernel: h = relu(X@Wslice + bias) -> hFrag order. 1024 blocks =
// (b, ks, mh); 256 thr = 4 waves; block tile 128 m x 64 d over k=512
// (16 steps of 32). LDS: single X-tile [128][40] bf16 = 10 KB.
// Per step: AWRITE(regs loaded 2 steps ago) | issue B(kb+1), A(kb+2) |
// lds_barrier | ds_read 2 A-frags | 8 MFMA (B regs from last step) |
// lds_barrier. No vmcnt drain anywhere in the loop.
// ---------------------------------------------------------------------------
__global__ __launch_bounds__(256, 4) void lin_kernel(
    const float* __restrict__ X, const unsigned short* __restrict__ Wf,
    const float* __restrict__ bias, unsigned short* __restrict__ hF) {
    __shared__ unsigned short xt[128 * 40];

    const int W_ = (blockIdx.x & 7) * 128 + (blockIdx.x >> 3);  // XCD chunk
    const int mh = W_ & 1;
    const int ks = (W_ >> 1) & 7;
    const int b  = W_ >> 4;

    const int tid = threadIdx.x;
    const int lane = tid & 63, w = tid >> 6;     // wave 0..3
    const int lrow = lane & 15, quad = lane >> 4;

    // staging: thread = 64 B (16 f32) of one m-row, wave covers 32 rows
    const float* xsrc = X + (size_t)b * 131072
                          + (size_t)(mh * 128 + (tid >> 1)) * 512 + (tid & 1) * 16;
    const int xw = (tid >> 1) * 40 + (tid & 1) * 16;

    const unsigned short* wfp = Wf + (size_t)ks * 32768 + lrow * 32 + quad * 8;

    float bv[4];
#pragma unroll
    for (int dt = 0; dt < 4; ++dt) bv[dt] = bias[ks * 64 + dt * 16 + lrow];

    floatx4 acc[2][4];
    const floatx4 fzero = {0.f, 0.f, 0.f, 0.f};
#pragma unroll
    for (int g = 0; g < 2; ++g)
#pragma unroll
        for (int j = 0; j < 4; ++j) acc[g][j] = fzero;

    float4 ra[4], rb[4];
    short8 wc[4], wn[4];

#define LLOAD(r, kb) do {                                               \
        r[0] = *(const float4*)(xsrc + (kb) * 32);                      \
        r[1] = *(const float4*)(xsrc + (kb) * 32 + 4);                  \
        r[2] = *(const float4*)(xsrc + (kb) * 32 + 8);                  \
        r[3] = *(const float4*)(xsrc + (kb) * 32 + 12);                 \
    } while (0)
#define LWRITE(r) do {                                                  \
        union { short8 s; unsigned u[4]; } t0_, t1_;                    \
        t0_.u[0] = pk2bf(r[0].x, r[0].y); t0_.u[1] = pk2bf(r[0].z, r[0].w); \
        t0_.u[2] = pk2bf(r[1].x, r[1].y); t0_.u[3] = pk2bf(r[1].z, r[1].w); \
        t1_.u[0] = pk2bf(r[2].x, r[2].y); t1_.u[1] = pk2bf(r[2].z, r[2].w); \
        t1_.u[2] = pk2bf(r[3].x, r[3].y); t1_.u[3] = pk2bf(r[3].z, r[3].w); \
        *(short8*)(xt + xw) = t0_.s;                                    \
        *(short8*)(xt + xw + 8) = t1_.s;                                \
    } while (0)

    LLOAD(ra, 0);
    LLOAD(rb, 1);
#pragma unroll
    for (int dt = 0; dt < 4; ++dt) wc[dt] = *(const short8*)(wfp + dt * 512);

#pragma unroll
    for (int kb = 0; kb < 16; ++kb) {
        if (kb > 0) lds_barrier();           // all reads of step kb-1 done
        if (kb & 1) { LWRITE(rb); if (kb < 14) LLOAD(rb, kb + 2); }
        else        { LWRITE(ra); if (kb < 14) LLOAD(ra, kb + 2); }
        if (kb < 15) {
#pragma unroll
            for (int dt = 0; dt < 4; ++dt)
                wn[dt] = *(const short8*)(wfp + (kb + 1) * 2048 + dt * 512);
        }
        lds_barrier();                       // tile written, visible
        short8 a0 = *(const short8*)(xt + (w * 32 + lrow) * 40 + quad * 8);
        short8 a1 = *(const short8*)(xt + (w * 32 + 16 + lrow) * 40 + quad * 8);
#pragma unroll
        for (int dt = 0; dt < 4; ++dt) {
            acc[0][dt] = __builtin_amdgcn_mfma_f32_16x16x32_bf16(a0, wc[dt], acc[0][dt], 0, 0, 0);
            acc[1][dt] = __builtin_amdgcn_mfma_f32_16x16x32_bf16(a1, wc[dt], acc[1][dt], 0, 0, 0);
        }
#pragma unroll
        for (int dt = 0; dt < 4; ++dt) wc[dt] = wn[dt];
    }
#undef LLOAD
#undef LWRITE

    // epilogue -> hFrag: C row (quad*4+reg) = m, col (lane&15) = d.
    unsigned short* hs = hF + (size_t)(b * 8 + ks) * 16384 + (size_t)(mh * 4 + w) * 2048;
#pragma unroll
    for (int g = 0; g < 2; ++g) {
#pragma unroll
        for (int dt = 0; dt < 4; ++dt) {
            floatx4 c = acc[g][dt];
            uint2 pv;
            pv.x = pk2bf(fmaxf(c.x + bv[dt], 0.f), fmaxf(c.y + bv[dt], 0.f));
            pv.y = pk2bf(fmaxf(c.z + bv[dt], 0.f), fmaxf(c.w + bv[dt], 0.f));
            *(uint2*)(hs + dt * 512 + lrow * 32 + g * 16 + quad * 4) = pv;
        }
    }
}

// ---------------------------------------------------------------------------
// agg_kernel: out = adj @ h. 1024 blocks = (b, ks, nt); 256 thr = 4 waves;
// block tile 128 n x 64 d over m=256 (8 steps of 32). LDS: single adj-tile
// [128][40] bf16 = 10 KB. Same no-vmcnt-drain pipeline as lin_kernel.
// adj staged coalesced (each 128-B line fetched exactly once); B-frags are
// 16B/lane coalesced global loads from hFrag (32 KB slice, L2-hot).
// ---------------------------------------------------------------------------
__global__ __launch_bounds__(256, 4) void agg_kernel(
    const unsigned short* __restrict__ hF, const float* __restrict__ adj,
    float* __restrict__ out) {
    __shared__ unsigned short at[128 * 40];

    const int W_ = (blockIdx.x & 7) * 128 + (blockIdx.x >> 3);  // XCD chunk
    const int nt = W_ & 1;
    const int ks = (W_ >> 1) & 7;
    const int b  = W_ >> 4;

    const int tid = threadIdx.x;
    const int lane = tid & 63, w = tid >> 6;     // wave 0..3
    const int lrow = lane & 15, quad = lane >> 4;

    const float* asrc = adj + (size_t)(b * 8 + ks) * 65536
                            + (size_t)(nt * 128 + (tid >> 1)) * 256 + (tid & 1) * 16;
    const int aw = (tid >> 1) * 40 + (tid & 1) * 16;

    const unsigned short* hfp = hF + (size_t)(b * 8 + ks) * 16384 + lrow * 32 + quad * 8;

    floatx4 acc[2][4];
    const floatx4 fzero = {0.f, 0.f, 0.f, 0.f};
#pragma unroll
    for (int g = 0; g < 2; ++g)
#pragma unroll
        for (int j = 0; j < 4; ++j) acc[g][j] = fzero;

    float4 ra[4], rb[4];
    short8 hc[4], hn[4];

#define ALOAD(r, mt) do {                                               \
        r[0] = *(const float4*)(asrc + (mt) * 32);                      \
        r[1] = *(const float4*)(asrc + (mt) * 32 + 4);                  \
        r[2] = *(const float4*)(asrc + (mt) * 32 + 8);                  \
        r[3] = *(const float4*)(asrc + (mt) * 32 + 12);                 \
    } while (0)
#define AWRITE(r) do {                                                  \
        union { short8 s; unsigned u[4]; } t0_, t1_;                    \
        t0_.u[0] = pk2bf(r[0].x, r[0].y); t0_.u[1] = pk2bf(r[0].z, r[0].w); \
        t0_.u[2] = pk2bf(r[1].x, r[1].y); t0_.u[3] = pk2bf(r[1].z, r[1].w); \
        t1_.u[0] = pk2bf(r[2].x, r[2].y); t1_.u[1] = pk2bf(r[2].z, r[2].w); \
        t1_.u[2] = pk2bf(r[3].x, r[3].y); t1_.u[3] = pk2bf(r[3].z, r[3].w); \
        *(short8*)(at + aw) = t0_.s;                                    \
        *(short8*)(at + aw + 8) = t1_.s;                                \
    } while (0)

    ALOAD(ra, 0);
    ALOAD(rb, 1);
#pragma unroll
    for (int dt = 0; dt < 4; ++dt) hc[dt] = *(const short8*)(hfp + dt * 512);

#pragma unroll
    for (int mt = 0; mt < 8; ++mt) {
        if (mt > 0) lds_barrier();           // all reads of step mt-1 done
        if (mt & 1) { AWRITE(rb); if (mt < 6) ALOAD(rb, mt + 2); }
        else        { AWRITE(ra); if (mt < 6) ALOAD(ra, mt + 2); }
        if (mt < 7) {
#pragma unroll
            for (int dt = 0; dt < 4; ++dt)
                hn[dt] = *(const short8*)(hfp + (mt + 1) * 2048 + dt * 512);
        }
        lds_barrier();                       // tile written, visible
        short8 a0 = *(const short8*)(at + (w * 32 + lrow) * 40 + quad * 8);
        short8 a1 = *(const short8*)(at + (w * 32 + 16 + lrow) * 40 + quad * 8);
#pragma unroll
        for (int dt = 0; dt < 4; ++dt) {
            acc[0][dt] = __builtin_amdgcn_mfma_f32_16x16x32_bf16(a0, hc[dt], acc[0][dt], 0, 0, 0);
            acc[1][dt] = __builtin_amdgcn_mfma_f32_16x16x32_bf16(a1, hc[dt], acc[1][dt], 0, 0, 0);
        }
#pragma unroll
        for (int dt = 0; dt < 4; ++dt) hc[dt] = hn[dt];
    }
#undef ALOAD
#undef AWRITE

    // epilogue: C row (quad*4+reg) = n, col (lane&15) = d
#pragma unroll
    for (int g = 0; g < 2; ++g) {
        const int n0 = nt * 128 + w * 32 + g * 16 + quad * 4;
        float* dst = out + ((size_t)b * 256 + n0) * 512 + ks * 64 + lrow;
#pragma unroll
        for (int dt = 0; dt < 4; ++dt) {
            float* p = dst + dt * 16;
            p[0 * 512] = acc[g][dt].x;
            p[1 * 512] = acc[g][dt].y;
            p[2 * 512] = acc[g][dt].z;
            p[3 * 512] = acc[g][dt].w;
        }
    }
}

// ---------------------------------------------------------------------------
extern "C" void kernel_launch(void* const* d_in, const int* in_sizes, int n_in,
                              void* d_out, int out_size, void* d_ws, size_t ws_size,
                              hipStream_t stream) {
    const float* X    = (const float*)d_in[0];  // node_feats
    const float* adj  = (const float*)d_in[1];  // adj
    const float* W    = (const float*)d_in[2];  // weight
    const float* bias = (const float*)d_in[3];  // bias
    float* out = (float*)d_out;

    // workspace: Wfrag bf16 (512 KB) then hFrag bf16 (16.8 MB)
    unsigned short* Wf = (unsigned short*)d_ws;
    unsigned short* hF = Wf + 512 * 512;

    wfrag_kernel<<<128, 256, 0, stream>>>(W, Wf);
    lin_kernel<<<1024, 256, 0, stream>>>(X, Wf, bias, hF);
    agg_kernel<<<1024, 256, 0, stream>>>(hF, adj, out);
}